// Round 13
// baseline (248.249 us; speedup 1.0000x reference)
//
#include <hip/hip_runtime.h>
#include <math.h>

#define BB  32
#define CCH 1024
#define HH  64
#define WW  64
#define JJ  128
#define NP  4
#define HID 128

typedef float f4 __attribute__((ext_vector_type(4)));
typedef __attribute__((ext_vector_type(8))) short bf8_t;   // 8 bf16 (4 VGPRs)
typedef __attribute__((ext_vector_type(4))) float f32x4;
typedef __attribute__((ext_vector_type(4))) unsigned short us4;
typedef __attribute__((ext_vector_type(16))) unsigned short us16;

__device__ __forceinline__ unsigned short f2bf(float x) {
  union { float f; unsigned int u; } v; v.f = x;
  unsigned int u = v.u;
  return (unsigned short)((u + 0x7FFFu + ((u >> 16) & 1u)) >> 16);
}

__device__ __forceinline__ float bilin(const float* pl, float ix, float iy) {
  float x0f = floorf(ix), y0f = floorf(iy);
  float wx1 = ix - x0f, wx0 = 1.0f - wx1;
  float wy1 = iy - y0f, wy0 = 1.0f - wy1;
  int x0 = (int)x0f, y0 = (int)y0f;
  int x1 = x0 + 1, y1 = y0 + 1;
  float v = 0.0f;
  if (y0 >= 0 && y0 < HH) {
    if (x0 >= 0 && x0 < WW) v += pl[y0*WW + x0] * (wx0*wy0);
    if (x1 >= 0 && x1 < WW) v += pl[y0*WW + x1] * (wx1*wy0);
  }
  if (y1 >= 0 && y1 < HH) {
    if (x0 >= 0 && x0 < WW) v += pl[y1*WW + x0] * (wx0*wy1);
    if (x1 >= 0 && x1 < WW) v += pl[y1*WW + x1] * (wx1*wy1);
  }
  return v;
}

// Gather seed with direct transposed output: thread j gathers 16 channels'
// bilinear corners and writes 32 B straight into seedT[b][j][c0..c0+16).
// grid (CCH/16, BB), 128 threads. kp in [-1,1) => corners in-bounds.
__global__ __launch_bounds__(128) void k_seedG2(const float* __restrict__ feat,
                                                const float* __restrict__ kp,
                                                unsigned short* __restrict__ seedT) {
  int c0 = blockIdx.x * 16, b = blockIdx.y;
  int j = threadIdx.x;
  float gx = kp[((size_t)b*JJ + j)*2 + 0];
  float gy = kp[((size_t)b*JJ + j)*2 + 1];
  float ix = (gx + 1.0f) * 0.5f * (float)(WW - 1);
  float iy = (gy + 1.0f) * 0.5f * (float)(HH - 1);
  float x0f = floorf(ix), y0f = floorf(iy);
  float wx1 = ix - x0f, wx0 = 1.0f - wx1;
  float wy1 = iy - y0f, wy0 = 1.0f - wy1;
  int x0 = (int)x0f, y0 = (int)y0f;
  int x1 = min(x0 + 1, WW - 1), y1 = min(y0 + 1, HH - 1);
  float w00 = wx0*wy0, w01 = wx1*wy0, w10 = wx0*wy1, w11 = wx1*wy1;
  int o00 = y0*WW + x0, o01 = y0*WW + x1, o10 = y1*WW + x0, o11 = y1*WW + x1;

  const float* pb = feat + ((size_t)(b*CCH + c0)) * (size_t)(HH*WW);
  us16 out16;
  #pragma unroll
  for (int cc = 0; cc < 16; ++cc) {
    const float* pl = pb + (size_t)cc * (HH*WW);
    float v = pl[o00]*w00 + pl[o01]*w01 + pl[o10]*w10 + pl[o11]*w11;
    out16[cc] = f2bf(v);
  }
  *(us16*)&seedT[((size_t)b*JJ + j)*CCH + c0] = out16;
}

// MFMA hidden GEMM + fused layer2/softmax/grids epilogue; W staged from f32
// with inline bf16 cast.
// grid (2 m, 2 jh, 32 b). Block: 64 j rows x 128 o, K=1024.
__global__ __launch_bounds__(256) void k_mlp3(const unsigned short* __restrict__ seedT,
                                              const float* __restrict__ w_off1,
                                              const float* __restrict__ w_att1,
                                              const float* __restrict__ b_off1,
                                              const float* __restrict__ b_att1,
                                              const float* __restrict__ kp,
                                              const float* __restrict__ w_off2,
                                              const float* __restrict__ b_off2,
                                              const float* __restrict__ w_att2,
                                              const float* __restrict__ b_att2,
                                              float* __restrict__ grids,
                                              float* __restrict__ attw) {
  int m = blockIdx.x, jh = blockIdx.y, b = blockIdx.z;
  __shared__ __align__(16) unsigned short sA[64][72];   // [j][k], +8 pad
  __shared__ __align__(16) unsigned short sB[128][72];  // [o][k], +8 pad
  __shared__ __align__(16) float sH[64][132];           // hidden tile
  __shared__ float sO[64][13];
  int t = threadIdx.x;
  int w = t >> 6, l = t & 63;
  int lr = l & 15, lg = l >> 4;
  f32x4 acc[8];
  #pragma unroll
  for (int ot = 0; ot < 8; ++ot) acc[ot] = (f32x4)0.0f;

  const unsigned short* At = seedT + ((size_t)b * JJ + jh * 64) * CCH;  // [j][c] bf16
  const float* Wt = m ? w_att1 : w_off1;                                // [o][c] f32

  for (int kc = 0; kc < 16; ++kc) {
    int k0 = kc * 64;
    // stage A tile: 64 rows x 64 k = 512 x 16B, 2 per thread
    #pragma unroll
    for (int q = 0; q < 2; ++q) {
      int idx = q * 256 + t;
      int r = idx >> 3, s = idx & 7;
      *(bf8_t*)&sA[r][s*8] = *(const bf8_t*)&At[(size_t)r*CCH + k0 + s*8];
    }
    // stage B tile from f32 with inline cast: 128 rows x 64 k = 2048 f4, 8/thread
    #pragma unroll
    for (int q = 0; q < 8; ++q) {
      int idx = q * 256 + t;
      int r = idx >> 4, s = idx & 15;
      f4 v = *(const f4*)&Wt[(size_t)r*CCH + k0 + s*4];
      us4 u;
      u[0] = f2bf(v[0]); u[1] = f2bf(v[1]); u[2] = f2bf(v[2]); u[3] = f2bf(v[3]);
      *(us4*)&sB[r][s*4] = u;
    }
    __syncthreads();
    #pragma unroll
    for (int ks = 0; ks < 2; ++ks) {
      int koff = ks*32 + lg*8;
      bf8_t a0 = *(const bf8_t*)&sA[w*16 + lr][koff];
      #pragma unroll
      for (int ot = 0; ot < 8; ++ot) {
        bf8_t bb = *(const bf8_t*)&sB[ot*16 + lr][koff];
        acc[ot] = __builtin_amdgcn_mfma_f32_16x16x32_bf16(a0, bb, acc[ot], 0, 0, 0);
      }
    }
    __syncthreads();
  }

  // hidden tile -> LDS with bias+relu
  const float* bias = m ? b_att1 : b_off1;
  #pragma unroll
  for (int ot = 0; ot < 8; ++ot) {
    int o = ot*16 + lr;
    float bo = bias[o];
    #pragma unroll
    for (int r = 0; r < 4; ++r) {
      int jl = w*16 + lg*4 + r;
      sH[jl][o] = fmaxf(acc[ot][r] + bo, 0.0f);
    }
  }
  __syncthreads();

  // layer2: m=0 -> 8 offset outputs; m=1 -> 4 attention logits
  if (m == 0) {
    for (int idx = t; idx < 64*8; idx += 256) {
      int jl = idx >> 3, p = idx & 7;
      const float* w2 = w_off2 + (size_t)p * HID;
      float sum = b_off2[p];
      #pragma unroll 8
      for (int o = 0; o < HID; ++o) sum += w2[o] * sH[jl][o];
      sO[jl][p] = sum;
    }
  } else {
    for (int idx = t; idx < 64*4; idx += 256) {
      int jl = idx >> 2, p = idx & 3;
      const float* w2 = w_att2 + (size_t)p * HID;
      float sum = b_att2[p];
      #pragma unroll 8
      for (int o = 0; o < HID; ++o) sum += w2[o] * sH[jl][o];
      sO[jl][p] = sum;
    }
  }
  __syncthreads();

  if (t < 64) {
    int j = jh*64 + t;
    if (m == 0) {
      float gx = kp[((size_t)b*JJ + j)*2 + 0];
      float gy = kp[((size_t)b*JJ + j)*2 + 1];
      const float sc = 2.0f / 63.0f;
      #pragma unroll
      for (int n = 0; n < NP; ++n) {
        grids[(((size_t)b*JJ + j)*NP + n)*2 + 0] = gx + sO[t][2*n + 0]*sc;
        grids[(((size_t)b*JJ + j)*NP + n)*2 + 1] = gy + sO[t][2*n + 1]*sc;
      }
    } else {
      float a0 = sO[t][0], a1 = sO[t][1], a2 = sO[t][2], a3 = sO[t][3];
      float mx = fmaxf(fmaxf(a0, a1), fmaxf(a2, a3));
      float e0 = expf(a0 - mx), e1 = expf(a1 - mx);
      float e2 = expf(a2 - mx), e3 = expf(a3 - mx);
      float inv = 1.0f / (e0 + e1 + e2 + e3);
      attw[((size_t)b*JJ + j)*NP + 0] = e0*inv;
      attw[((size_t)b*JJ + j)*NP + 1] = e1*inv;
      attw[((size_t)b*JJ + j)*NP + 2] = e2*inv;
      attw[((size_t)b*JJ + j)*NP + 3] = e3*inv;
    }
  }
}

// Fused gather + attention blend, direct transposed output.
// REVERSE batch order (L3 tail reuse); normal f4 stores.
__global__ __launch_bounds__(256) void k_fuse2(const float* __restrict__ feat,
                                               const float* __restrict__ grids,
                                               const float* __restrict__ attw,
                                               float* __restrict__ out) {
  int c0 = blockIdx.x * 16;
  int b = (BB - 1) - blockIdx.y;      // reverse order for L3 tail reuse
  __shared__ __align__(16) float plane[2][HH*WW];   // 32 KB
  __shared__ float sT[JJ][17];
  __shared__ float sG[JJ*NP*2];
  __shared__ float sAw[JJ*NP];
  int t = threadIdx.x;
  const f4* gb = (const f4*)(grids + (size_t)b*JJ*NP*2);
  const f4* ab = (const f4*)(attw  + (size_t)b*JJ*NP);
  ((f4*)sG)[t] = gb[t];
  if (t < 128) ((f4*)sAw)[t] = ab[t];

  const float* base = feat + ((size_t)(b*CCH + c0)) * (size_t)(HH*WW);
  f4 r[4];
  {
    const f4* p0 = (const f4*)base;
    #pragma unroll
    for (int q = 0; q < 4; ++q) r[q] = p0[t + q*256];
    f4* d = (f4*)plane[0];
    #pragma unroll
    for (int q = 0; q < 4; ++q) d[t + q*256] = r[q];
  }
  __syncthreads();

  for (int i = 0; i < 16; ++i) {
    int cur = i & 1;
    if (i < 15) {
      const f4* pn = (const f4*)(base + (size_t)(i + 1) * (HH*WW));
      #pragma unroll
      for (int q = 0; q < 4; ++q) r[q] = pn[t + q*256];
    }
    if (t < JJ) {
      float acc = 0.0f;
      #pragma unroll
      for (int n = 0; n < NP; ++n) {
        float gx = sG[(t*NP + n)*2 + 0];
        float gy = sG[(t*NP + n)*2 + 1];
        float ix = (gx + 1.0f) * 0.5f * (float)(WW - 1);
        float iy = (gy + 1.0f) * 0.5f * (float)(HH - 1);
        acc += sAw[t*NP + n] * bilin(plane[cur], ix, iy);
      }
      sT[t][i] = acc;
    }
    __syncthreads();
    if (i < 15) {
      f4* d = (f4*)plane[cur ^ 1];
      #pragma unroll
      for (int q = 0; q < 4; ++q) d[t + q*256] = r[q];
    }
    __syncthreads();
  }

  if (t < JJ) {
    f4* dst = (f4*)&out[((size_t)b*JJ + t)*CCH + c0];
    #pragma unroll
    for (int q = 0; q < 4; ++q) {
      f4 v;
      v[0] = sT[t][q*4 + 0]; v[1] = sT[t][q*4 + 1];
      v[2] = sT[t][q*4 + 2]; v[3] = sT[t][q*4 + 3];
      dst[q] = v;
    }
  }
}

extern "C" void kernel_launch(void* const* d_in, const int* in_sizes, int n_in,
                              void* d_out, int out_size, void* d_ws, size_t ws_size,
                              hipStream_t stream) {
  const float* feat   = (const float*)d_in[0];
  const float* kp     = (const float*)d_in[1];
  const float* w_off1 = (const float*)d_in[2];
  const float* b_off1 = (const float*)d_in[3];
  const float* w_off2 = (const float*)d_in[4];
  const float* b_off2 = (const float*)d_in[5];
  const float* w_att1 = (const float*)d_in[6];
  const float* b_att1 = (const float*)d_in[7];
  const float* w_att2 = (const float*)d_in[8];
  const float* b_att2 = (const float*)d_in[9];
  float* out = (float*)d_out;

  // workspace (float offsets), 8.6 MB total:
  //   grids        : 0        .. 32768     (32*128*4*2 f32)
  //   attw         : 32768    .. 49152     (32*128*4 f32)
  //   seedT(ushort): 49152    .. 2146304   (32*128*1024 bf16, [b][j][c])
  float* ws = (float*)d_ws;
  float*          grids = ws;
  float*          attwb = ws + (size_t)32768;
  unsigned short* seedT = (unsigned short*)(ws + (size_t)49152);

  k_seedG2<<<dim3(CCH/16, BB), 128, 0, stream>>>(feat, kp, seedT);
  k_mlp3  <<<dim3(2, 2, BB), 256, 0, stream>>>(seedT, w_off1, w_att1, b_off1, b_att1,
                                               kp, w_off2, b_off2, w_att2, b_att2,
                                               grids, attwb);
  k_fuse2 <<<dim3(CCH/16, BB), 256, 0, stream>>>(feat, grids, attwb, out);
}

// Round 14
// 220.266 us; speedup vs baseline: 1.1270x; 1.1270x over previous
//
#include <hip/hip_runtime.h>
#include <math.h>

#define BB  32
#define CCH 1024
#define HH  64
#define WW  64
#define JJ  128
#define NP  4
#define HID 128

typedef float f4 __attribute__((ext_vector_type(4)));
typedef __attribute__((ext_vector_type(8))) short bf8_t;   // 8 bf16 (4 VGPRs)
typedef __attribute__((ext_vector_type(4))) float f32x4;
typedef __attribute__((ext_vector_type(4))) unsigned short us4;
typedef __attribute__((ext_vector_type(16))) unsigned short us16;

__device__ __forceinline__ unsigned short f2bf(float x) {
  union { float f; unsigned int u; } v; v.f = x;
  unsigned int u = v.u;
  return (unsigned short)((u + 0x7FFFu + ((u >> 16) & 1u)) >> 16);
}

__device__ __forceinline__ float bilin(const float* pl, float ix, float iy) {
  float x0f = floorf(ix), y0f = floorf(iy);
  float wx1 = ix - x0f, wx0 = 1.0f - wx1;
  float wy1 = iy - y0f, wy0 = 1.0f - wy1;
  int x0 = (int)x0f, y0 = (int)y0f;
  int x1 = x0 + 1, y1 = y0 + 1;
  float v = 0.0f;
  if (y0 >= 0 && y0 < HH) {
    if (x0 >= 0 && x0 < WW) v += pl[y0*WW + x0] * (wx0*wy0);
    if (x1 >= 0 && x1 < WW) v += pl[y0*WW + x1] * (wx1*wy0);
  }
  if (y1 >= 0 && y1 < HH) {
    if (x0 >= 0 && x0 < WW) v += pl[y1*WW + x0] * (wx0*wy1);
    if (x1 >= 0 && x1 < WW) v += pl[y1*WW + x1] * (wx1*wy1);
  }
  return v;
}

// Gather-based seed (R12-proven): seedB[b][c][j] = bf16(bilinear(feat[b,c], kp[b,j])).
__global__ __launch_bounds__(128) void k_seedG(const float* __restrict__ feat,
                                               const float* __restrict__ kp,
                                               unsigned short* __restrict__ seedB) {
  int c = blockIdx.x, b = blockIdx.y;
  int j = threadIdx.x;
  float gx = kp[((size_t)b*JJ + j)*2 + 0];
  float gy = kp[((size_t)b*JJ + j)*2 + 1];
  float ix = (gx + 1.0f) * 0.5f * (float)(WW - 1);
  float iy = (gy + 1.0f) * 0.5f * (float)(HH - 1);
  float x0f = floorf(ix), y0f = floorf(iy);
  float wx1 = ix - x0f, wx0 = 1.0f - wx1;
  float wy1 = iy - y0f, wy0 = 1.0f - wy1;
  int x0 = (int)x0f, y0 = (int)y0f;
  int x1 = min(x0 + 1, WW - 1), y1 = min(y0 + 1, HH - 1);
  const float* pb = feat + ((size_t)(b*CCH + c)) * (size_t)(HH*WW);
  float v00 = pb[y0*WW + x0], v01 = pb[y0*WW + x1];
  float v10 = pb[y1*WW + x0], v11 = pb[y1*WW + x1];
  float v = (v00*wx0 + v01*wx1)*wy0 + (v10*wx0 + v11*wx1)*wy1;
  seedB[((size_t)(b*CCH + c))*JJ + j] = f2bf(v);
}

// MFMA hidden GEMM + fused layer2/softmax/grids epilogue.
// A staged DIRECTLY from seedB [b][c][j] with in-LDS transpose (k_str eliminated).
// W staged from f32 with inline bf16 cast.
// grid (2 m, 2 jh, 32 b). Block: 64 j rows x 128 o, K=1024.
__global__ __launch_bounds__(256) void k_mlp3(const unsigned short* __restrict__ seedB,
                                              const float* __restrict__ w_off1,
                                              const float* __restrict__ w_att1,
                                              const float* __restrict__ b_off1,
                                              const float* __restrict__ b_att1,
                                              const float* __restrict__ kp,
                                              const float* __restrict__ w_off2,
                                              const float* __restrict__ b_off2,
                                              const float* __restrict__ w_att2,
                                              const float* __restrict__ b_att2,
                                              float* __restrict__ grids,
                                              float* __restrict__ attw) {
  int m = blockIdx.x, jh = blockIdx.y, b = blockIdx.z;
  __shared__ __align__(16) unsigned short sA[64][72];   // [j][k], +8 pad
  __shared__ __align__(16) unsigned short sB[128][72];  // [o][k], +8 pad
  __shared__ __align__(16) float sH[64][132];           // hidden tile
  __shared__ float sO[64][13];
  int t = threadIdx.x;
  int w = t >> 6, l = t & 63;
  int lr = l & 15, lg = l >> 4;
  f32x4 acc[8];
  #pragma unroll
  for (int ot = 0; ot < 8; ++ot) acc[ot] = (f32x4)0.0f;

  const unsigned short* Sb = seedB + (size_t)b * CCH * JJ;   // [c][j] bf16
  const float* Wt = m ? w_att1 : w_off1;                     // [o][c] f32
  int j0 = jh * 64;

  // staging roles for A: thread t -> c-row r=t>>2 (0..63), j-quarter q=t&3
  int ar = t >> 2, aq = t & 3;

  for (int kc = 0; kc < 16; ++kc) {
    int k0 = kc * 64;
    // stage A tile from seedB [c][j] with transpose: read 32B contiguous in j,
    // scatter b16 into sA[j][c].
    {
      us16 v = *(const us16*)&Sb[(size_t)(k0 + ar)*JJ + j0 + aq*16];
      #pragma unroll
      for (int k = 0; k < 16; ++k) sA[aq*16 + k][ar] = v[k];
    }
    // stage B tile from f32 with inline cast: 128 rows x 64 k = 2048 f4, 8/thread
    #pragma unroll
    for (int q = 0; q < 8; ++q) {
      int idx = q * 256 + t;
      int r = idx >> 4, s = idx & 15;
      f4 v = *(const f4*)&Wt[(size_t)r*CCH + k0 + s*4];
      us4 u;
      u[0] = f2bf(v[0]); u[1] = f2bf(v[1]); u[2] = f2bf(v[2]); u[3] = f2bf(v[3]);
      *(us4*)&sB[r][s*4] = u;
    }
    __syncthreads();
    #pragma unroll
    for (int ks = 0; ks < 2; ++ks) {
      int koff = ks*32 + lg*8;
      bf8_t a0 = *(const bf8_t*)&sA[w*16 + lr][koff];
      #pragma unroll
      for (int ot = 0; ot < 8; ++ot) {
        bf8_t bb = *(const bf8_t*)&sB[ot*16 + lr][koff];
        acc[ot] = __builtin_amdgcn_mfma_f32_16x16x32_bf16(a0, bb, acc[ot], 0, 0, 0);
      }
    }
    __syncthreads();
  }

  // hidden tile -> LDS with bias+relu
  const float* bias = m ? b_att1 : b_off1;
  #pragma unroll
  for (int ot = 0; ot < 8; ++ot) {
    int o = ot*16 + lr;
    float bo = bias[o];
    #pragma unroll
    for (int r = 0; r < 4; ++r) {
      int jl = w*16 + lg*4 + r;
      sH[jl][o] = fmaxf(acc[ot][r] + bo, 0.0f);
    }
  }
  __syncthreads();

  // layer2: m=0 -> 8 offset outputs; m=1 -> 4 attention logits
  if (m == 0) {
    for (int idx = t; idx < 64*8; idx += 256) {
      int jl = idx >> 3, p = idx & 7;
      const float* w2 = w_off2 + (size_t)p * HID;
      float sum = b_off2[p];
      #pragma unroll 8
      for (int o = 0; o < HID; ++o) sum += w2[o] * sH[jl][o];
      sO[jl][p] = sum;
    }
  } else {
    for (int idx = t; idx < 64*4; idx += 256) {
      int jl = idx >> 2, p = idx & 3;
      const float* w2 = w_att2 + (size_t)p * HID;
      float sum = b_att2[p];
      #pragma unroll 8
      for (int o = 0; o < HID; ++o) sum += w2[o] * sH[jl][o];
      sO[jl][p] = sum;
    }
  }
  __syncthreads();

  if (t < 64) {
    int j = j0 + t;
    if (m == 0) {
      float gx = kp[((size_t)b*JJ + j)*2 + 0];
      float gy = kp[((size_t)b*JJ + j)*2 + 1];
      const float sc = 2.0f / 63.0f;
      #pragma unroll
      for (int n = 0; n < NP; ++n) {
        grids[(((size_t)b*JJ + j)*NP + n)*2 + 0] = gx + sO[t][2*n + 0]*sc;
        grids[(((size_t)b*JJ + j)*NP + n)*2 + 1] = gy + sO[t][2*n + 1]*sc;
      }
    } else {
      float a0 = sO[t][0], a1 = sO[t][1], a2 = sO[t][2], a3 = sO[t][3];
      float mx = fmaxf(fmaxf(a0, a1), fmaxf(a2, a3));
      float e0 = expf(a0 - mx), e1 = expf(a1 - mx);
      float e2 = expf(a2 - mx), e3 = expf(a3 - mx);
      float inv = 1.0f / (e0 + e1 + e2 + e3);
      attw[((size_t)b*JJ + j)*NP + 0] = e0*inv;
      attw[((size_t)b*JJ + j)*NP + 1] = e1*inv;
      attw[((size_t)b*JJ + j)*NP + 2] = e2*inv;
      attw[((size_t)b*JJ + j)*NP + 3] = e3*inv;
    }
  }
}

// Fused gather + attention blend, direct transposed output.
// REVERSE batch order (L3 tail reuse); normal f4 stores.
__global__ __launch_bounds__(256) void k_fuse2(const float* __restrict__ feat,
                                               const float* __restrict__ grids,
                                               const float* __restrict__ attw,
                                               float* __restrict__ out) {
  int c0 = blockIdx.x * 16;
  int b = (BB - 1) - blockIdx.y;      // reverse order for L3 tail reuse
  __shared__ __align__(16) float plane[2][HH*WW];   // 32 KB
  __shared__ float sT[JJ][17];
  __shared__ float sG[JJ*NP*2];
  __shared__ float sAw[JJ*NP];
  int t = threadIdx.x;
  const f4* gb = (const f4*)(grids + (size_t)b*JJ*NP*2);
  const f4* ab = (const f4*)(attw  + (size_t)b*JJ*NP);
  ((f4*)sG)[t] = gb[t];
  if (t < 128) ((f4*)sAw)[t] = ab[t];

  const float* base = feat + ((size_t)(b*CCH + c0)) * (size_t)(HH*WW);
  f4 r[4];
  {
    const f4* p0 = (const f4*)base;
    #pragma unroll
    for (int q = 0; q < 4; ++q) r[q] = p0[t + q*256];
    f4* d = (f4*)plane[0];
    #pragma unroll
    for (int q = 0; q < 4; ++q) d[t + q*256] = r[q];
  }
  __syncthreads();

  for (int i = 0; i < 16; ++i) {
    int cur = i & 1;
    if (i < 15) {
      const f4* pn = (const f4*)(base + (size_t)(i + 1) * (HH*WW));
      #pragma unroll
      for (int q = 0; q < 4; ++q) r[q] = pn[t + q*256];
    }
    if (t < JJ) {
      float acc = 0.0f;
      #pragma unroll
      for (int n = 0; n < NP; ++n) {
        float gx = sG[(t*NP + n)*2 + 0];
        float gy = sG[(t*NP + n)*2 + 1];
        float ix = (gx + 1.0f) * 0.5f * (float)(WW - 1);
        float iy = (gy + 1.0f) * 0.5f * (float)(HH - 1);
        acc += sAw[t*NP + n] * bilin(plane[cur], ix, iy);
      }
      sT[t][i] = acc;
    }
    __syncthreads();
    if (i < 15) {
      f4* d = (f4*)plane[cur ^ 1];
      #pragma unroll
      for (int q = 0; q < 4; ++q) d[t + q*256] = r[q];
    }
    __syncthreads();
  }

  if (t < JJ) {
    f4* dst = (f4*)&out[((size_t)b*JJ + t)*CCH + c0];
    #pragma unroll
    for (int q = 0; q < 4; ++q) {
      f4 v;
      v[0] = sT[t][q*4 + 0]; v[1] = sT[t][q*4 + 1];
      v[2] = sT[t][q*4 + 2]; v[3] = sT[t][q*4 + 3];
      dst[q] = v;
    }
  }
}

extern "C" void kernel_launch(void* const* d_in, const int* in_sizes, int n_in,
                              void* d_out, int out_size, void* d_ws, size_t ws_size,
                              hipStream_t stream) {
  const float* feat   = (const float*)d_in[0];
  const float* kp     = (const float*)d_in[1];
  const float* w_off1 = (const float*)d_in[2];
  const float* b_off1 = (const float*)d_in[3];
  const float* w_off2 = (const float*)d_in[4];
  const float* b_off2 = (const float*)d_in[5];
  const float* w_att1 = (const float*)d_in[6];
  const float* b_att1 = (const float*)d_in[7];
  const float* w_att2 = (const float*)d_in[8];
  const float* b_att2 = (const float*)d_in[9];
  float* out = (float*)d_out;

  // workspace (float offsets), 8.6 MB total:
  //   grids        : 0        .. 32768     (32*128*4*2 f32)
  //   attw         : 32768    .. 49152     (32*128*4 f32)
  //   seedB(ushort): 49152    .. 2146304   (32*1024*128 bf16, [b][c][j])
  float* ws = (float*)d_ws;
  float*          grids = ws;
  float*          attwb = ws + (size_t)32768;
  unsigned short* seedB = (unsigned short*)(ws + (size_t)49152);

  k_seedG<<<dim3(CCH, BB), 128, 0, stream>>>(feat, kp, seedB);
  k_mlp3 <<<dim3(2, 2, BB), 256, 0, stream>>>(seedB, w_off1, w_att1, b_off1, b_att1,
                                              kp, w_off2, b_off2, w_att2, b_att2,
                                              grids, attwb);
  k_fuse2<<<dim3(CCH/16, BB), 256, 0, stream>>>(feat, grids, attwb, out);
}